// Round 5
// baseline (183.642 us; speedup 1.0000x reference)
//
#include <hip/hip_runtime.h>

// Fully-fused deformable-conv net, flat cell-parallel, v3 (spill-free).
// cg = img*196 + cell; B*196 = 3136*256 exactly -> every lane active.
// Key change vs round 4: p (position-within-pool-cell) is the OUTER loop.
// Each position computes its 8 conv channels to completion in a[8], then
// folds into the running max m[8] (relu commutes with max; m init 0).
// Live set: m[8]+a[8]+nb[9]+temps (~30 floats) vs round 4's acc[32]+nb[16]
// (48+), which overflowed the compiler's 44-VGPR target and spilled to
// scratch (WRITE_SIZE 5 MB, 3x instr bloat).

#define WP 30
#define NPOS 784
#define NPOOL 1568
#define CELLS 196

__global__ __launch_bounds__(256, 4) void deform_net_kernel(
    const float* __restrict__ x,       // (B,1,28,28)
    const float* __restrict__ w_off,   // (18,1,3,3)
    const float* __restrict__ b_off,   // (18,)
    const float* __restrict__ w_conv,  // (8,1,3,3)
    const float* __restrict__ w_fc,    // (10,1568)
    const float* __restrict__ b_fc,    // (10,)
    float* __restrict__ out,           // (B,10), pre-zeroed
    int B)
{
    __shared__ float xs[3][900];       // 3 padded images, 10.8 KB

    const int tid      = threadIdx.x;
    const int cell0    = blockIdx.x << 8;
    const int img_base = cell0 / CELLS;

    // Stage up to 3 zero-padded 30x30 images into LDS.
    for (int i = tid; i < 2700; i += 256) {
        int s = i / 900;
        int j = i - s * 900;
        int img = img_base + s;
        float v = 0.f;
        if (img < B) {
            int r = j / WP, c = j - r * WP;
            if (r >= 1 && r <= 28 && c >= 1 && c <= 28)
                v = x[(size_t)img * NPOS + (r - 1) * 28 + (c - 1)];
        }
        xs[s][j] = v;
    }
    __syncthreads();

    const int cg  = cell0 + tid;
    const int img = cg / CELLS;
    float fc[10];
    #pragma unroll
    for (int c = 0; c < 10; c++) fc[c] = 0.f;

    if (cg < B * CELLS) {
        const int cell = cg - img * CELLS;
        const float* __restrict__ xsp = xs[img - img_base];
        const int ph = cell / 14, pw = cell - ph * 14;
        const int h0 = 2 * ph, w0 = 2 * pw;

        float m[8];
        #pragma unroll
        for (int o = 0; o < 8; o++) m[o] = 0.f;   // relu folded into max

        #pragma unroll
        for (int p = 0; p < 4; p++) {             // position within pool cell
            const int h = h0 + (p >> 1), w = w0 + (p & 1);
            const float* tap = xsp + h * WP + w;

            float nb[9];                           // this position's 3x3 taps
            #pragma unroll
            for (int i = 0; i < 3; i++)
                #pragma unroll
                for (int j = 0; j < 3; j++)
                    nb[i * 3 + j] = tap[i * WP + j];

            float a[8];
            #pragma unroll
            for (int o = 0; o < 8; o++) a[o] = 0.f;

            #pragma unroll
            for (int k = 0; k < 9; k++) {          // deform tap
                // offset channels k (x) and k+9 (y)
                float offx = b_off[k], offy = b_off[k + 9];
                #pragma unroll
                for (int t = 0; t < 9; t++) {
                    offx = fmaf(w_off[k * 9 + t],       nb[t], offx);
                    offy = fmaf(w_off[(k + 9) * 9 + t], nb[t], offy);
                }

                // sample point in padded frame
                float p_x = (float)(h + k / 3) + offx;
                float p_y = (float)(w + k % 3) + offy;

                float q0x = floorf(p_x), q0y = floorf(p_y);
                float qltx = fminf(fmaxf(q0x,       0.f), 29.f);
                float qlty = fminf(fmaxf(q0y,       0.f), 29.f);
                float qrbx = fminf(fmaxf(q0x + 1.f, 0.f), 29.f);
                float qrby = fminf(fmaxf(q0y + 1.f, 0.f), 29.f);
                float px   = fminf(fmaxf(p_x,       0.f), 29.f);
                float py   = fminf(fmaxf(p_y,       0.f), 29.f);

                float gltx = 1.f + (qltx - px);
                float glty = 1.f + (qlty - py);
                float grbx = 1.f - (qrbx - px);
                float grby = 1.f - (qrby - py);

                const float* row_l = xsp + (int)qltx * WP;
                const float* row_r = xsp + (int)qrbx * WP;
                const int ily = (int)qlty, iry = (int)qrby;

                float s = gltx * (glty * row_l[ily] + grby * row_l[iry])
                        + grbx * (glty * row_r[ily] + grby * row_r[iry]);

                #pragma unroll
                for (int o = 0; o < 8; o++)
                    a[o] = fmaf(w_conv[o * 9 + k], s, a[o]);
            }

            #pragma unroll
            for (int o = 0; o < 8; o++) m[o] = fmaxf(m[o], a[o]);
        }

        // FC partials: 10 base addresses, 8 imm-offset loads each.
        const float* wbase = w_fc + cell;
        #pragma unroll
        for (int c = 0; c < 10; c++) {
            const float* wr = wbase + c * NPOOL;
            #pragma unroll
            for (int o = 0; o < 8; o++)
                fc[c] = fmaf(m[o], wr[o * CELLS], fc[c]);
        }
        if (cell == 0) {          // fold bias in exactly once per image
            #pragma unroll
            for (int c = 0; c < 10; c++) fc[c] += b_fc[c];
        }
    }

    // Per-wave segmented butterfly reduction (a wave spans <=2 images).
    const int lane = tid & 63;
    const int wave_first_cell = cell0 + (tid & ~63);
    const int seg0 = wave_first_cell / CELLS;
    const int seg1 = (wave_first_cell + 63) / CELLS;

    if (seg0 == seg1) {
        #pragma unroll
        for (int c = 0; c < 10; c++) {
            float v = fc[c];
            #pragma unroll
            for (int sh = 32; sh > 0; sh >>= 1) v += __shfl_down(v, sh, 64);
            if (lane == 0 && seg0 < B) atomicAdd(&out[seg0 * 10 + c], v);
        }
    } else {
        const bool in0 = (img == seg0);
        #pragma unroll
        for (int c = 0; c < 10; c++) {
            float v0 = in0 ? fc[c] : 0.f;
            float v1 = fc[c] - v0;
            #pragma unroll
            for (int sh = 32; sh > 0; sh >>= 1) {
                v0 += __shfl_down(v0, sh, 64);
                v1 += __shfl_down(v1, sh, 64);
            }
            if (lane == 0) {
                if (seg0 < B) atomicAdd(&out[seg0 * 10 + c], v0);
                if (seg1 < B) atomicAdd(&out[seg1 * 10 + c], v1);
            }
        }
    }
}

extern "C" void kernel_launch(void* const* d_in, const int* in_sizes, int n_in,
                              void* d_out, int out_size, void* d_ws, size_t ws_size,
                              hipStream_t stream) {
    const float* x      = (const float*)d_in[0];
    const float* w_off  = (const float*)d_in[1];
    const float* b_off  = (const float*)d_in[2];
    const float* w_conv = (const float*)d_in[3];
    const float* w_fc   = (const float*)d_in[4];
    const float* b_fc   = (const float*)d_in[5];
    float* out = (float*)d_out;

    const int B = in_sizes[0] / NPOS;
    const int grid = (B * CELLS + 255) / 256;

    hipMemsetAsync(d_out, 0, (size_t)out_size * sizeof(float), stream);
    deform_net_kernel<<<grid, 256, 0, stream>>>(x, w_off, b_off, w_conv,
                                                w_fc, b_fc, out, B);
}